// Round 6
// baseline (265.066 us; speedup 1.0000x reference)
//
#include <hip/hip_runtime.h>

#define NN 100000
#define NE 3200000
#define DD 64
#define KE 64                 // target edges per worker
#define NW (NE / KE)          // 50000 workers

typedef unsigned int uint32;

// ---------------------------------------------------------------------------
// bf16 round-to-nearest-even of an f32 (inputs finite).
// ---------------------------------------------------------------------------
__device__ inline uint32 bf16_rne(float f) {
    uint32 u = __float_as_uint(f);
    return (u + 0x7fffu + ((u >> 16) & 1u)) >> 16;
}

// ---------------------------------------------------------------------------
// int64 vs int32 index detection (see round-1 notes).
// ---------------------------------------------------------------------------
__global__ void detect_kernel(const void* rowbuf, int* flag) {
    const int* p = (const int*)rowbuf;
    int lo = p[NE / 2];
    int hi = p[NE / 2 + 1];
    *flag = (hi == 0 && lo != 0) ? 1 : 0;
}

// ---------------------------------------------------------------------------
// row_ptr[r] = lower_bound(adj_row, r); row r owns edges [rp[r], rp[r+1]).
// ---------------------------------------------------------------------------
__global__ void rowptr_kernel(const void* rowbuf, const int* __restrict__ flag,
                              int* __restrict__ rp) {
    int r = blockIdx.x * blockDim.x + threadIdx.x;
    if (r > NN) return;
    int is64 = *flag;
    int lo = 0, hi = NE;
    if (is64) {
        const long long* row = (const long long*)rowbuf;
        while (lo < hi) {
            int mid = (lo + hi) >> 1;
            if (row[mid] < (long long)r) lo = mid + 1; else hi = mid;
        }
    } else {
        const int* row = (const int*)rowbuf;
        while (lo < hi) {
            int mid = (lo + hi) >> 1;
            if (row[mid] < r) lo = mid + 1; else hi = mid;
        }
    }
    rp[r] = lo;
}

// ---------------------------------------------------------------------------
// ws[w] = first row r with rp[r] >= 64*w  (worker w exclusively owns rows
// [ws[w], ws[w+1]) -- includes empty rows; union over w covers [0, NN)).
// ---------------------------------------------------------------------------
__global__ void wstart_kernel(const int* __restrict__ rp, int* __restrict__ ws) {
    int w = blockIdx.x * blockDim.x + threadIdx.x;
    if (w > NW) return;
    if (w == NW) { ws[w] = NN; return; }
    int target = w * KE;
    int lo = 0, hi = NN;
    while (lo < hi) {
        int mid = (lo + hi) >> 1;
        if (rp[mid] < target) lo = mid + 1; else hi = mid;
    }
    ws[w] = lo;
}

// ---------------------------------------------------------------------------
// Pack each edge into 4B: bits 31..17 = bf16(val) sans sign (val >= 0),
// bits 16..0 = col (NN < 2^17). 32 zero-records of padding at the tail.
// ---------------------------------------------------------------------------
__global__ void pack_kernel(const void* colbuf, const float* __restrict__ val,
                            const int* __restrict__ flag,
                            uint32* __restrict__ erec) {
    int e = blockIdx.x * blockDim.x + threadIdx.x;
    if (e >= NE + 32) return;
    uint32 o = 0u;
    if (e < NE) {
        int c = *flag ? (int)((const long long*)colbuf)[e]
                      : ((const int*)colbuf)[e];
        o = ((bf16_rne(val[e]) & 0x7fffu) << 17) | (uint32)c;
    }
    erec[e] = o;
}

// ---------------------------------------------------------------------------
// f32 -> packed bf16 (uint = 2 features), 8 elements/thread.
// ---------------------------------------------------------------------------
__global__ void cvt_bf16_kernel(const float* __restrict__ X,
                                uint32* __restrict__ Y, int n) {
    int i = (blockIdx.x * blockDim.x + threadIdx.x) * 8;
    if (i >= n) return;
    float4 a = *(const float4*)(X + i);
    float4 b = *(const float4*)(X + i + 4);
    uint4 o;
    o.x = bf16_rne(a.x) | (bf16_rne(a.y) << 16);
    o.y = bf16_rne(a.z) | (bf16_rne(a.w) << 16);
    o.z = bf16_rne(b.x) | (bf16_rne(b.y) << 16);
    o.w = bf16_rne(b.z) | (bf16_rne(b.w) << 16);
    *(uint4*)(Y + i / 2) = o;
}

// ---------------------------------------------------------------------------
// SpMM with exclusive row ownership. Half-wave (32 lanes) worker streams its
// edge range in 32-edge batches with a 16-deep gather pipeline. Lane sl holds
// features {2sl, 2sl+1}. On row boundary (e >= re) the accumulated row is
// stored ONCE as packed bf16 (no atomics, no pre-zero; flush cascade also
// emits empty rows). Batch-overrun edges only touch the accumulator after
// the worker's final flush -> harmless.
// ---------------------------------------------------------------------------
#define ISSUE(G, I) {                                           \
    uint32 t_ = (uint32)__shfl((int)rw, (I), 32);               \
    G = Xq[(size_t)(t_ & 0x1ffffu) * 32u + (uint32)sl]; }

#define ACCUM(G, I) {                                           \
    uint32 t_ = (uint32)__shfl((int)rw, (I), 32);               \
    while (rr < r1 && e0 + (I) >= re) {                         \
        ob[(size_t)rr * 32 + sl] =                              \
            bf16_rne(ax) | (bf16_rne(ay) << 16);                \
        ax = 0.f; ay = 0.f; ++rr;                               \
        int nxt_ = rr + 1; if (nxt_ > NN) nxt_ = NN;            \
        re = rp[nxt_];                                          \
    }                                                           \
    float vi_ = __uint_as_float((t_ >> 17) << 16);              \
    float lo_ = __uint_as_float(G << 16);                       \
    float hi_ = __uint_as_float(G & 0xffff0000u);               \
    ax = fmaf(vi_, lo_, ax); ay = fmaf(vi_, hi_, ay); }

__global__ __launch_bounds__(256) void spmm_kernel(
    const uint32* __restrict__ Xq, const uint32* __restrict__ erec,
    const int* __restrict__ rp, const int* __restrict__ ws,
    uint32* __restrict__ ob) {
    int worker = (blockIdx.x * blockDim.x + threadIdx.x) >> 5;
    int sl = threadIdx.x & 31;
    if (worker >= NW) return;

    int rr = ws[worker];
    int r1 = ws[worker + 1];
    if (rr >= r1) return;

    int eb = rp[rr];
    int ee = rp[r1];
    int re = rp[rr + 1];
    float ax = 0.f, ay = 0.f;

    for (int e0 = eb; e0 < ee; e0 += 32) {
        uint32 rw = erec[e0 + sl];   // this lane's edge record
        uint32 g0, g1, g2, g3, g4, g5, g6, g7;
        uint32 h0, h1, h2, h3, h4, h5, h6, h7;
        ISSUE(g0, 0)  ISSUE(g1, 1)  ISSUE(g2, 2)  ISSUE(g3, 3)
        ISSUE(g4, 4)  ISSUE(g5, 5)  ISSUE(g6, 6)  ISSUE(g7, 7)
        ISSUE(h0, 8)  ISSUE(h1, 9)  ISSUE(h2, 10) ISSUE(h3, 11)
        ISSUE(h4, 12) ISSUE(h5, 13) ISSUE(h6, 14) ISSUE(h7, 15)
        ACCUM(g0, 0)  ACCUM(g1, 1)  ACCUM(g2, 2)  ACCUM(g3, 3)
        ACCUM(g4, 4)  ACCUM(g5, 5)  ACCUM(g6, 6)  ACCUM(g7, 7)
        ISSUE(g0, 16) ISSUE(g1, 17) ISSUE(g2, 18) ISSUE(g3, 19)
        ISSUE(g4, 20) ISSUE(g5, 21) ISSUE(g6, 22) ISSUE(g7, 23)
        ACCUM(h0, 8)  ACCUM(h1, 9)  ACCUM(h2, 10) ACCUM(h3, 11)
        ACCUM(h4, 12) ACCUM(h5, 13) ACCUM(h6, 14) ACCUM(h7, 15)
        ISSUE(h0, 24) ISSUE(h1, 25) ISSUE(h2, 26) ISSUE(h3, 27)
        ISSUE(h4, 28) ISSUE(h5, 29) ISSUE(h6, 30) ISSUE(h7, 31)
        ACCUM(g0, 16) ACCUM(g1, 17) ACCUM(g2, 18) ACCUM(g3, 19)
        ACCUM(g4, 20) ACCUM(g5, 21) ACCUM(g6, 22) ACCUM(g7, 23)
        ACCUM(h0, 24) ACCUM(h1, 25) ACCUM(h2, 26) ACCUM(h3, 27)
        ACCUM(h4, 28) ACCUM(h5, 29) ACCUM(h6, 30) ACCUM(h7, 31)
    }
    // drain: last row + trailing empty rows
    while (rr < r1) {
        ob[(size_t)rr * 32 + sl] = bf16_rne(ax) | (bf16_rne(ay) << 16);
        ax = 0.f; ay = 0.f; ++rr;
    }
}

// ---------------------------------------------------------------------------
// Dense per-node GEMM on packed-bf16 input:
//   y[row,:] = act(unpack(Bb[row,:]) @ W + b)
// One thread per node, 64 f32 accumulators, W staged in LDS as float4
// (uniform-address broadcast, conflict-free).
// ---------------------------------------------------------------------------
template <bool OUT_BF16>
__global__ __launch_bounds__(256) void gemm_kernel(
    const uint32* __restrict__ Bb, const float* __restrict__ W,
    const float* __restrict__ bias, void* __restrict__ outv, int leaky) {
    __shared__ float4 sW[DD * 16];   // sW[k*16 + j4] = W[k][4j4 .. 4j4+3]
    __shared__ float  sb[DD];
    for (int i = threadIdx.x; i < DD * 16; i += 256)
        sW[i] = ((const float4*)W)[i];
    if (threadIdx.x < DD) sb[threadIdx.x] = bias[threadIdx.x];
    __syncthreads();

    int row = blockIdx.x * 256 + threadIdx.x;
    if (row >= NN) return;

    float acc[DD];
#pragma unroll
    for (int j = 0; j < DD; ++j) acc[j] = sb[j];

    const uint4* Bp = (const uint4*)(Bb + (size_t)row * 32);
#pragma unroll
    for (int q4 = 0; q4 < 8; ++q4) {
        uint4 u4 = Bp[q4];
        uint32 us[4] = {u4.x, u4.y, u4.z, u4.w};
#pragma unroll
        for (int t = 0; t < 4; ++t) {
            int k = q4 * 8 + t * 2;
            float x0 = __uint_as_float(us[t] << 16);
            float x1 = __uint_as_float(us[t] & 0xffff0000u);
#pragma unroll
            for (int j4 = 0; j4 < 16; ++j4) {
                float4 w0 = sW[k * 16 + j4];
                float4 w1 = sW[(k + 1) * 16 + j4];
                acc[4 * j4 + 0] = fmaf(x0, w0.x, acc[4 * j4 + 0]);
                acc[4 * j4 + 1] = fmaf(x0, w0.y, acc[4 * j4 + 1]);
                acc[4 * j4 + 2] = fmaf(x0, w0.z, acc[4 * j4 + 2]);
                acc[4 * j4 + 3] = fmaf(x0, w0.w, acc[4 * j4 + 3]);
                acc[4 * j4 + 0] = fmaf(x1, w1.x, acc[4 * j4 + 0]);
                acc[4 * j4 + 1] = fmaf(x1, w1.y, acc[4 * j4 + 1]);
                acc[4 * j4 + 2] = fmaf(x1, w1.z, acc[4 * j4 + 2]);
                acc[4 * j4 + 3] = fmaf(x1, w1.w, acc[4 * j4 + 3]);
            }
        }
    }

    if (leaky) {
#pragma unroll
        for (int j = 0; j < DD; ++j)
            acc[j] = (acc[j] >= 0.f) ? acc[j] : 0.2f * acc[j];
    }

    if (OUT_BF16) {
        uint32* o = (uint32*)outv + (size_t)row * 32;
#pragma unroll
        for (int q = 0; q < 32; ++q)
            o[q] = bf16_rne(acc[2 * q]) | (bf16_rne(acc[2 * q + 1]) << 16);
    } else {
        float* o = (float*)outv + (size_t)row * DD;
#pragma unroll
        for (int j = 0; j < DD; ++j) o[j] = acc[j];
    }
}

// ---------------------------------------------------------------------------
extern "C" void kernel_launch(void* const* d_in, const int* in_sizes, int n_in,
                              void* d_out, int out_size, void* d_ws, size_t ws_size,
                              hipStream_t stream) {
    const float* x       = (const float*)d_in[0];
    const void*  adj_row = d_in[1];
    const void*  adj_col = d_in[2];
    const float* adj_val = (const float*)d_in[3];
    const float* W1      = (const float*)d_in[4];
    const float* b1      = (const float*)d_in[5];
    const float* W2      = (const float*)d_in[6];
    const float* b2      = (const float*)d_in[7];
    float*       out     = (float*)d_out;

    // ws: bufA [NN*32 u32] | bufB [NN*32 u32] | erec [NE+32 u32] | rp | ws | flag
    uint32* bufA = (uint32*)d_ws;                    // xb, later hb
    uint32* bufB = bufA + (size_t)NN * 32;           // B1b, later B2b
    uint32* erec = bufB + (size_t)NN * 32;
    int*    rp   = (int*)(erec + NE + 32);
    int*    wst  = rp + (NN + 1);
    int*    flag = wst + (NW + 1);

    detect_kernel<<<1, 1, 0, stream>>>(adj_row, flag);
    rowptr_kernel<<<(NN + 1 + 255) / 256, 256, 0, stream>>>(adj_row, flag, rp);
    wstart_kernel<<<(NW + 1 + 255) / 256, 256, 0, stream>>>(rp, wst);
    pack_kernel<<<(NE + 32 + 255) / 256, 256, 0, stream>>>(adj_col, adj_val,
                                                           flag, erec);
    const int n = NN * DD;
    cvt_bf16_kernel<<<(n / 8 + 255) / 256, 256, 0, stream>>>(x, bufA, n);

    const int spmm_blocks = (NW * 32) / 256;   // 6250
    const int gemm_blocks = (NN + 255) / 256;  // 391

    // layer 1: B1b(bufB) = A xb(bufA) ; hb(bufA) = bf16(LReLU(B1b W1 + b1))
    spmm_kernel<<<spmm_blocks, 256, 0, stream>>>(bufA, erec, rp, wst, bufB);
    gemm_kernel<true><<<gemm_blocks, 256, 0, stream>>>(bufB, W1, b1, bufA, 1);

    // layer 2: B2b(bufB) = A hb(bufA) ; out = B2b W2 + b2 (f32)
    spmm_kernel<<<spmm_blocks, 256, 0, stream>>>(bufA, erec, rp, wst, bufB);
    gemm_kernel<false><<<gemm_blocks, 256, 0, stream>>>(bufB, W2, b2, out, 0);
}